// Round 2
// baseline (35.218 us; speedup 1.0000x reference)
//
#include <hip/hip_runtime.h>
#include <hip/hip_cooperative_groups.h>

namespace cg = cooperative_groups;

#define T_LEN 4096
#define BLOCK 1024
#define EPT 4            // elements per thread = T_LEN / BLOCK
#define NWAVES 16        // BLOCK / 64
#define RADIUS_I 20

__global__ __launch_bounds__(BLOCK)
void aml_fused(const float* __restrict__ vel,
               const int* __restrict__ bnd,
               const int* __restrict__ msk,
               float* __restrict__ partials,  // [2 * nrows] in d_ws
               float* __restrict__ out,
               int nrows) {
    cg::grid_group grid = cg::this_grid();

    const int row  = blockIdx.x;
    const int tid  = threadIdx.x;
    const int lane = tid & 63;
    const int wave = tid >> 6;

    __shared__ unsigned long long sbm[T_LEN / 64];  // boundary bitmask, word w = elems [64w,64w+64)
    __shared__ float swsum[NWAVES];
    __shared__ float sredN[NWAVES];
    __shared__ float sredD[NWAVES];
    __shared__ float sscale;

    const size_t rowoff = (size_t)row * T_LEN;
    const float4 v4 = reinterpret_cast<const float4*>(vel + rowoff)[tid];
    const int4   b4 = reinterpret_cast<const int4*>(bnd + rowoff)[tid];
    const int4   m4 = reinterpret_cast<const int4*>(msk + rowoff)[tid];

    float vv[EPT], mf[EPT];
    int be[EPT];
    unsigned long long nib = 0ULL;
    {
        const float vs[EPT] = {v4.x, v4.y, v4.z, v4.w};
        const int   bs[EPT] = {b4.x, b4.y, b4.z, b4.w};
        const int   ms[EPT] = {m4.x, m4.y, m4.z, m4.w};
#pragma unroll
        for (int i = 0; i < EPT; ++i) {
            mf[i] = ms[i] ? 1.0f : 0.0f;
            vv[i] = vs[i] * mf[i];
            be[i] = (bs[i] != 0 || ms[i] == 0) ? 1 : 0;
            nib |= ((unsigned long long)be[i]) << i;
        }
    }

    // ---- build boundary bitmask: 16 threads per 64-bit word, OR-reduce via shfl ----
    unsigned long long wbits = nib << ((tid & 15) * 4);
#pragma unroll
    for (int off = 1; off < 16; off <<= 1)
        wbits |= __shfl_xor(wbits, off, 64);
    if ((tid & 15) == 0) sbm[tid >> 4] = wbits;
    __syncthreads();

    // ---- block-wide inclusive prefix sum of vv (the cumsum) ----
    float p[EPT];
    p[0] = vv[0];
#pragma unroll
    for (int i = 1; i < EPT; ++i) p[i] = p[i - 1] + vv[i];
    const float tsum = p[EPT - 1];

    float sc = tsum;
#pragma unroll
    for (int off = 1; off < 64; off <<= 1) {
        float n = __shfl_up(sc, off, 64);
        if (lane >= off) sc += n;
    }
    if (lane == 63) swsum[wave] = sc;
    __syncthreads();

    if (wave == 0 && lane < NWAVES) {
        float w = swsum[lane];
#pragma unroll
        for (int off = 1; off < NWAVES; off <<= 1) {
            float n = __shfl_up(w, off, 64);
            if (lane >= off) w += n;
        }
        swsum[lane] = w;
    }
    __syncthreads();

    const float base = (wave == 0) ? 0.0f : swsum[wave - 1];
    const float lane_excl = sc - tsum;
    float pred[EPT];
#pragma unroll
    for (int i = 0; i < EPT; ++i) pred[i] = base + lane_excl + p[i];

    // ---- distance transform via bitmask (clamped at 20) ----
    // This thread's 4 elements all live in word wi = tid>>4.
    const int wi = tid >> 4;
    const unsigned long long W0  = sbm[wi];
    const unsigned long long Wm1 = (wi > 0) ? sbm[wi - 1] : 0ULL;
    const unsigned long long Wp1 = (wi < T_LEN / 64 - 1) ? sbm[wi + 1] : 0ULL;

    float gt[EPT];
#pragma unroll
    for (int i = 0; i < EPT; ++i) {
        const int t   = tid * EPT + i;
        const int pos = t & 63;
        if (be[i]) {
            gt[i] = 0.0f;
        } else {
            int d = min(t + 1, T_LEN - t);   // virtual boundaries at -1 and T
            // backward (positions < t)
            const unsigned long long low = (pos == 0) ? 0ULL
                                         : (W0 & ((1ULL << pos) - 1ULL));
            if (low) {
                const int h = 63 - __builtin_clzll(low);
                d = min(d, pos - h);
            } else if (Wm1) {
                d = min(d, pos + 1 + __builtin_clzll(Wm1));
            }
            // forward (positions > t)
            const unsigned long long high = (W0 >> pos) >> 1;
            if (high) {
                d = min(d, __builtin_ctzll(high) + 1);
            } else if (Wp1) {
                d = min(d, 64 - pos + __builtin_ctzll(Wp1));
            }
            gt[i] = (float)min(d, RADIUS_I);
        }
    }

    // ---- row max of gt -> scale ----
    float dmax = gt[0];
#pragma unroll
    for (int i = 1; i < EPT; ++i) dmax = fmaxf(dmax, gt[i]);
#pragma unroll
    for (int off = 32; off > 0; off >>= 1)
        dmax = fmaxf(dmax, __shfl_xor(dmax, off, 64));
    if (lane == 0) sredN[wave] = dmax;
    __syncthreads();
    if (tid == 0) {
        float m = sredN[0];
        for (int i = 1; i < NWAVES; ++i) m = fmaxf(m, sredN[i]);
        sscale = m + 1e-6f;
    }
    __syncthreads();
    const float scale = sscale;

    // ---- numerator / denominator partial sums ----
    float num = 0.0f, den = 0.0f;
#pragma unroll
    for (int i = 0; i < EPT; ++i) {
        num += fabsf(pred[i] - gt[i]) * mf[i];
        den += mf[i];
    }
#pragma unroll
    for (int off = 32; off > 0; off >>= 1) {
        num += __shfl_xor(num, off, 64);
        den += __shfl_xor(den, off, 64);
    }
    if (lane == 0) { sredN[wave] = num; sredD[wave] = den; }
    __syncthreads();
    if (tid == 0) {
        float ns = 0.0f, ds = 0.0f;
        for (int i = 0; i < NWAVES; ++i) { ns += sredN[i]; ds += sredD[i]; }
        partials[row] = ns / scale;
        partials[nrows + row] = ds;
    }

    // ---- grid-wide combine ----
    grid.sync();
    if (row == 0 && tid == 0) {
        float num_all = 0.0f, den_all = 0.0f;
        for (int r = 0; r < nrows; ++r) {
            num_all += partials[r];
            den_all += partials[nrows + r];
        }
        out[0] = num_all / (den_all + 1e-6f);
    }
}

extern "C" void kernel_launch(void* const* d_in, const int* in_sizes, int n_in,
                              void* d_out, int out_size, void* d_ws, size_t ws_size,
                              hipStream_t stream) {
    const float* vel = (const float*)d_in[0];
    const int*   bnd = (const int*)d_in[1];
    const int*   msk = (const int*)d_in[2];
    const int total = in_sizes[0];
    int nrows = total / T_LEN;

    float* partials = (float*)d_ws;
    float* out = (float*)d_out;

    void* args[] = {(void*)&vel, (void*)&bnd, (void*)&msk,
                    (void*)&partials, (void*)&out, (void*)&nrows};
    hipLaunchCooperativeKernel((const void*)aml_fused,
                               dim3(nrows), dim3(BLOCK), args, 0, stream);
}

// Round 3
// 23.430 us; speedup vs baseline: 1.5031x; 1.5031x over previous
//
#include <hip/hip_runtime.h>

#define T_LEN 4096
#define BLOCK 1024
#define NROWS 8
#define TPR 128          // threads per row (2 waves)
#define EPT 32           // elements per thread = T_LEN / TPR
#define NWAVES 16
#define RADIUS_I 20

// One block does the entire problem: 8 rows x 4096, 2 waves per row,
// 32 elems per thread. Each thread owns exactly one 32-bit boundary word.
__global__ __launch_bounds__(BLOCK)
void aml_oneblock(const float* __restrict__ vel,
                  const int* __restrict__ bnd,
                  const int* __restrict__ msk,
                  float* __restrict__ out) {
    const int tid  = threadIdx.x;
    const int lane = tid & 63;
    const int wave = tid >> 6;
    const int row  = tid >> 7;          // 0..7
    const int tir  = tid & (TPR - 1);   // thread-in-row 0..127 == word index

    __shared__ unsigned int sbm[NROWS * TPR];  // boundary bits, 1 word / thread
    __shared__ float wtot[NWAVES];             // wave cumsum totals
    __shared__ float wnum[NWAVES];
    __shared__ float wden[NWAVES];
    __shared__ float wmax[NWAVES];

    const size_t rowoff = (size_t)row * T_LEN + (size_t)tir * EPT;
    const float* vp = vel + rowoff;
    const int*   bp = bnd + rowoff;
    const int*   mp = msk + rowoff;

    // ---- load boundaries/mask -> bit words; velocities -> masked prefix ----
    unsigned int W0 = 0u, mbits = 0u;
#pragma unroll
    for (int j = 0; j < EPT / 4; ++j) {
        const int4 b4 = reinterpret_cast<const int4*>(bp)[j];
        const int4 m4 = reinterpret_cast<const int4*>(mp)[j];
        const int bs[4] = {b4.x, b4.y, b4.z, b4.w};
        const int ms[4] = {m4.x, m4.y, m4.z, m4.w};
#pragma unroll
        for (int k = 0; k < 4; ++k) {
            const int i = j * 4 + k;
            if (ms[k]) mbits |= 1u << i;
            if (bs[k] != 0 || ms[k] == 0) W0 |= 1u << i;
        }
    }
    sbm[tid] = W0;

    float p[EPT];
    {
        float run = 0.0f;
#pragma unroll
        for (int j = 0; j < EPT / 4; ++j) {
            const float4 v4 = reinterpret_cast<const float4*>(vp)[j];
            const float vs[4] = {v4.x, v4.y, v4.z, v4.w};
#pragma unroll
            for (int k = 0; k < 4; ++k) {
                const int i = j * 4 + k;
                run += ((mbits >> i) & 1u) ? vs[k] : 0.0f;
                p[i] = run;
            }
        }
    }
    const float tsum = p[EPT - 1];

    // ---- wave inclusive scan of per-thread totals ----
    float sc = tsum;
#pragma unroll
    for (int off = 1; off < 64; off <<= 1) {
        float n = __shfl_up(sc, off, 64);
        if (lane >= off) sc += n;
    }
    if (lane == 63) wtot[wave] = sc;
    __syncthreads();   // covers sbm[] and wtot[]

    // row-level exclusive base: odd wave of the pair adds even wave's total
    float rb = sc - tsum;                       // exclusive within wave
    if (wave & 1) rb += wtot[wave - 1];

    // ---- distance transform via 32-bit words (clamped at 20) ----
    const unsigned int Wm1 = (tir > 0)       ? sbm[tid - 1] : 0u;
    const unsigned int Wp1 = (tir < TPR - 1) ? sbm[tid + 1] : 0u;
    const int clz_m1 = Wm1 ? __builtin_clz(Wm1) : 0;   // hoisted
    const int ctz_p1 = Wp1 ? __builtin_ctz(Wp1) : 0;

    float num = 0.0f, dmax = 0.0f;
#pragma unroll
    for (int i = 0; i < EPT; ++i) {
        const int t = tir * EPT + i;
        float gtv;
        if ((W0 >> i) & 1u) {
            gtv = 0.0f;
        } else {
            int d = min(t + 1, T_LEN - t);   // virtual boundaries at -1 and T
            const unsigned int low = (i == 0) ? 0u : (W0 & ((1u << i) - 1u));
            if (low)      d = min(d, i - (31 - __builtin_clz(low)));
            else if (Wm1) d = min(d, i + 1 + clz_m1);
            const unsigned int high = (W0 >> i) >> 1;
            if (high)     d = min(d, __builtin_ctz(high) + 1);
            else if (Wp1) d = min(d, EPT - i + ctz_p1);
            gtv = (float)min(d, RADIUS_I);
        }
        dmax = fmaxf(dmax, gtv);
        const float pred = rb + p[i];
        num += ((mbits >> i) & 1u) ? fabsf(pred - gtv) : 0.0f;
    }
    float den = (float)__builtin_popcount(mbits);

    // ---- wave reductions ----
#pragma unroll
    for (int off = 32; off > 0; off >>= 1) {
        num += __shfl_xor(num, off, 64);
        den += __shfl_xor(den, off, 64);
        dmax = fmaxf(dmax, __shfl_xor(dmax, off, 64));
    }
    if (lane == 0) { wnum[wave] = num; wden[wave] = den; wmax[wave] = dmax; }
    __syncthreads();

    // ---- final combine (one thread) ----
    if (tid == 0) {
        float num_all = 0.0f, den_all = 0.0f;
#pragma unroll
        for (int r = 0; r < NROWS; ++r) {
            const float scale = fmaxf(wmax[2 * r], wmax[2 * r + 1]) + 1e-6f;
            num_all += (wnum[2 * r] + wnum[2 * r + 1]) / scale;
            den_all += wden[2 * r] + wden[2 * r + 1];
        }
        out[0] = num_all / (den_all + 1e-6f);
    }
}

extern "C" void kernel_launch(void* const* d_in, const int* in_sizes, int n_in,
                              void* d_out, int out_size, void* d_ws, size_t ws_size,
                              hipStream_t stream) {
    const float* vel = (const float*)d_in[0];
    const int*   bnd = (const int*)d_in[1];
    const int*   msk = (const int*)d_in[2];
    (void)in_sizes; (void)n_in; (void)d_ws; (void)ws_size; (void)out_size;

    aml_oneblock<<<1, BLOCK, 0, stream>>>(vel, bnd, msk, (float*)d_out);
}

// Round 4
// 12.608 us; speedup vs baseline: 2.7933x; 1.8583x over previous
//
#include <hip/hip_runtime.h>

#define T_LEN 4096
#define BLOCK 1024
#define EPT 4            // elements per thread = T_LEN / BLOCK
#define NWAVES 16        // BLOCK / 64
#define RADIUS_I 20
#define NROWS 8

// One block per row; last block to finish (device-scope atomic counter)
// performs the final combine. Counter correctness is independent of its
// initial value: each call adds exactly NROWS, and any NROWS consecutive
// integers contain exactly one value == NROWS-1 (mod NROWS).
__global__ __launch_bounds__(BLOCK)
void aml_row_kernel(const float* __restrict__ vel,
                    const int* __restrict__ bnd,
                    const int* __restrict__ msk,
                    float* __restrict__ partials,      // [2 * NROWS] in d_ws
                    unsigned int* __restrict__ counter, // in d_ws
                    float* __restrict__ out) {
    const int row  = blockIdx.x;
    const int tid  = threadIdx.x;
    const int lane = tid & 63;
    const int wave = tid >> 6;

    __shared__ unsigned long long sbm[T_LEN / 64];  // boundary bitmask
    __shared__ float swsum[NWAVES];
    __shared__ float sredN[NWAVES];
    __shared__ float sredD[NWAVES];

    const size_t rowoff = (size_t)row * T_LEN;
    const float4 v4 = reinterpret_cast<const float4*>(vel + rowoff)[tid];
    const int4   b4 = reinterpret_cast<const int4*>(bnd + rowoff)[tid];
    const int4   m4 = reinterpret_cast<const int4*>(msk + rowoff)[tid];

    float vv[EPT], mf[EPT];
    int be[EPT];
    unsigned long long nib = 0ULL;
    {
        const float vs[EPT] = {v4.x, v4.y, v4.z, v4.w};
        const int   bs[EPT] = {b4.x, b4.y, b4.z, b4.w};
        const int   ms[EPT] = {m4.x, m4.y, m4.z, m4.w};
#pragma unroll
        for (int i = 0; i < EPT; ++i) {
            mf[i] = ms[i] ? 1.0f : 0.0f;
            vv[i] = vs[i] * mf[i];
            be[i] = (bs[i] != 0 || ms[i] == 0) ? 1 : 0;
            nib |= ((unsigned long long)be[i]) << i;
        }
    }

    // ---- build boundary bitmask: 16 threads per 64-bit word ----
    unsigned long long wbits = nib << ((tid & 15) * 4);
#pragma unroll
    for (int off = 1; off < 16; off <<= 1)
        wbits |= __shfl_xor(wbits, off, 64);
    if ((tid & 15) == 0) sbm[tid >> 4] = wbits;
    __syncthreads();

    // ---- block-wide inclusive prefix sum (cumsum) ----
    float p[EPT];
    p[0] = vv[0];
#pragma unroll
    for (int i = 1; i < EPT; ++i) p[i] = p[i - 1] + vv[i];
    const float tsum = p[EPT - 1];

    float sc = tsum;
#pragma unroll
    for (int off = 1; off < 64; off <<= 1) {
        float n = __shfl_up(sc, off, 64);
        if (lane >= off) sc += n;
    }
    if (lane == 63) swsum[wave] = sc;
    __syncthreads();

    if (wave == 0 && lane < NWAVES) {
        float w = swsum[lane];
#pragma unroll
        for (int off = 1; off < NWAVES; off <<= 1) {
            float n = __shfl_up(w, off, 64);
            if (lane >= off) w += n;
        }
        swsum[lane] = w;
    }
    __syncthreads();

    const float base = (wave == 0) ? 0.0f : swsum[wave - 1];
    const float lane_excl = sc - tsum;
    float pred[EPT];
#pragma unroll
    for (int i = 0; i < EPT; ++i) pred[i] = base + lane_excl + p[i];

    // ---- distance transform via bitmask (clamped at 20) ----
    const int wi = tid >> 4;
    const unsigned long long W0  = sbm[wi];
    const unsigned long long Wm1 = (wi > 0) ? sbm[wi - 1] : 0ULL;
    const unsigned long long Wp1 = (wi < T_LEN / 64 - 1) ? sbm[wi + 1] : 0ULL;

    float gt[EPT];
#pragma unroll
    for (int i = 0; i < EPT; ++i) {
        const int t   = tid * EPT + i;
        const int pos = t & 63;
        if (be[i]) {
            gt[i] = 0.0f;
        } else {
            int d = min(t + 1, T_LEN - t);   // virtual boundaries at -1 and T
            const unsigned long long low = (pos == 0) ? 0ULL
                                         : (W0 & ((1ULL << pos) - 1ULL));
            if (low) {
                d = min(d, pos - (63 - __builtin_clzll(low)));
            } else if (Wm1) {
                d = min(d, pos + 1 + __builtin_clzll(Wm1));
            }
            const unsigned long long high = (W0 >> pos) >> 1;
            if (high) {
                d = min(d, __builtin_ctzll(high) + 1);
            } else if (Wp1) {
                d = min(d, 64 - pos + __builtin_ctzll(Wp1));
            }
            gt[i] = (float)min(d, RADIUS_I);
        }
    }

    // ---- row max of gt -> scale; num/den partials ----
    float dmax = gt[0];
#pragma unroll
    for (int i = 1; i < EPT; ++i) dmax = fmaxf(dmax, gt[i]);

    float num = 0.0f, den = 0.0f;
#pragma unroll
    for (int i = 0; i < EPT; ++i) {
        num += fabsf(pred[i] - gt[i]) * mf[i];
        den += mf[i];
    }
#pragma unroll
    for (int off = 32; off > 0; off >>= 1) {
        num += __shfl_xor(num, off, 64);
        den += __shfl_xor(den, off, 64);
        dmax = fmaxf(dmax, __shfl_xor(dmax, off, 64));
    }
    if (lane == 0) { sredN[wave] = num; sredD[wave] = den; swsum[wave] = dmax; }
    __syncthreads();

    if (tid == 0) {
        float ns = 0.0f, ds = 0.0f, m = swsum[0];
#pragma unroll
        for (int i = 0; i < NWAVES; ++i) {
            ns += sredN[i]; ds += sredD[i];
            m = fmaxf(m, swsum[i]);
        }
        const float scale = m + 1e-6f;
        __hip_atomic_store(&partials[row], ns / scale,
                           __ATOMIC_RELEASE, __HIP_MEMORY_SCOPE_AGENT);
        __hip_atomic_store(&partials[NROWS + row], ds,
                           __ATOMIC_RELEASE, __HIP_MEMORY_SCOPE_AGENT);
        const unsigned int old = __hip_atomic_fetch_add(counter, 1u,
                           __ATOMIC_ACQ_REL, __HIP_MEMORY_SCOPE_AGENT);
        if ((old % NROWS) == NROWS - 1) {
            // last block: combine
            float num_all = 0.0f, den_all = 0.0f;
#pragma unroll
            for (int r = 0; r < NROWS; ++r) {
                num_all += __hip_atomic_load(&partials[r],
                               __ATOMIC_ACQUIRE, __HIP_MEMORY_SCOPE_AGENT);
                den_all += __hip_atomic_load(&partials[NROWS + r],
                               __ATOMIC_ACQUIRE, __HIP_MEMORY_SCOPE_AGENT);
            }
            out[0] = num_all / (den_all + 1e-6f);
        }
    }
}

extern "C" void kernel_launch(void* const* d_in, const int* in_sizes, int n_in,
                              void* d_out, int out_size, void* d_ws, size_t ws_size,
                              hipStream_t stream) {
    const float* vel = (const float*)d_in[0];
    const int*   bnd = (const int*)d_in[1];
    const int*   msk = (const int*)d_in[2];
    (void)in_sizes; (void)n_in; (void)ws_size; (void)out_size;

    float* partials = (float*)d_ws;                       // 16 floats
    unsigned int* counter = (unsigned int*)((char*)d_ws + 64);

    aml_row_kernel<<<NROWS, BLOCK, 0, stream>>>(vel, bnd, msk, partials,
                                                counter, (float*)d_out);
}

// Round 5
// 10.094 us; speedup vs baseline: 3.4890x; 1.2491x over previous
//
#include <hip/hip_runtime.h>

#define T_LEN 4096
#define BLOCK 1024
#define EPT 4            // elements per thread = T_LEN / BLOCK
#define NWAVES 16        // BLOCK / 64
#define RADIUS_I 20
#define NROWS 8

// One block per row; last block to finish (device-scope atomic counter)
// performs the final combine. Counter correctness is independent of its
// initial value: each call adds exactly NROWS, and any NROWS consecutive
// integers contain exactly one value == NROWS-1 (mod NROWS).
// Memory ordering: partials stores/loads are RELAXED; the single
// fetch_add(ACQ_REL) on the counter provides both the release of the
// stores and the acquire for the loads -> loads issue in parallel.
__global__ __launch_bounds__(BLOCK)
void aml_row_kernel(const float* __restrict__ vel,
                    const int* __restrict__ bnd,
                    const int* __restrict__ msk,
                    float* __restrict__ partials,       // [2 * NROWS] in d_ws
                    unsigned int* __restrict__ counter, // in d_ws
                    float* __restrict__ out) {
    const int row  = blockIdx.x;
    const int tid  = threadIdx.x;
    const int lane = tid & 63;
    const int wave = tid >> 6;

    __shared__ unsigned long long sbm[T_LEN / 64];  // boundary bitmask
    __shared__ float swsum[NWAVES];
    __shared__ float sredN[NWAVES];
    __shared__ float sredD[NWAVES];

    const size_t rowoff = (size_t)row * T_LEN;
    const float4 v4 = reinterpret_cast<const float4*>(vel + rowoff)[tid];
    const int4   b4 = reinterpret_cast<const int4*>(bnd + rowoff)[tid];
    const int4   m4 = reinterpret_cast<const int4*>(msk + rowoff)[tid];

    float vv[EPT], mf[EPT];
    int be[EPT];
    unsigned long long nib = 0ULL;
    {
        const float vs[EPT] = {v4.x, v4.y, v4.z, v4.w};
        const int   bs[EPT] = {b4.x, b4.y, b4.z, b4.w};
        const int   ms[EPT] = {m4.x, m4.y, m4.z, m4.w};
#pragma unroll
        for (int i = 0; i < EPT; ++i) {
            mf[i] = ms[i] ? 1.0f : 0.0f;
            vv[i] = vs[i] * mf[i];
            be[i] = (bs[i] != 0 || ms[i] == 0) ? 1 : 0;
            nib |= ((unsigned long long)be[i]) << i;
        }
    }

    // ---- build boundary bitmask: 16 threads per 64-bit word ----
    unsigned long long wbits = nib << ((tid & 15) * 4);
#pragma unroll
    for (int off = 1; off < 16; off <<= 1)
        wbits |= __shfl_xor(wbits, off, 64);
    if ((tid & 15) == 0) sbm[tid >> 4] = wbits;
    __syncthreads();

    // ---- block-wide inclusive prefix sum (cumsum) ----
    float p[EPT];
    p[0] = vv[0];
#pragma unroll
    for (int i = 1; i < EPT; ++i) p[i] = p[i - 1] + vv[i];
    const float tsum = p[EPT - 1];

    float sc = tsum;
#pragma unroll
    for (int off = 1; off < 64; off <<= 1) {
        float n = __shfl_up(sc, off, 64);
        if (lane >= off) sc += n;
    }
    if (lane == 63) swsum[wave] = sc;
    __syncthreads();

    if (wave == 0 && lane < NWAVES) {
        float w = swsum[lane];
#pragma unroll
        for (int off = 1; off < NWAVES; off <<= 1) {
            float n = __shfl_up(w, off, 64);
            if (lane >= off) w += n;
        }
        swsum[lane] = w;
    }
    __syncthreads();

    const float base = (wave == 0) ? 0.0f : swsum[wave - 1];
    const float lane_excl = sc - tsum;
    float pred[EPT];
#pragma unroll
    for (int i = 0; i < EPT; ++i) pred[i] = base + lane_excl + p[i];

    // ---- distance transform via bitmask (clamped at 20) ----
    const int wi = tid >> 4;
    const unsigned long long W0  = sbm[wi];
    const unsigned long long Wm1 = (wi > 0) ? sbm[wi - 1] : 0ULL;
    const unsigned long long Wp1 = (wi < T_LEN / 64 - 1) ? sbm[wi + 1] : 0ULL;

    float gt[EPT];
#pragma unroll
    for (int i = 0; i < EPT; ++i) {
        const int t   = tid * EPT + i;
        const int pos = t & 63;
        if (be[i]) {
            gt[i] = 0.0f;
        } else {
            int d = min(t + 1, T_LEN - t);   // virtual boundaries at -1 and T
            const unsigned long long low = (pos == 0) ? 0ULL
                                         : (W0 & ((1ULL << pos) - 1ULL));
            if (low) {
                d = min(d, pos - (63 - __builtin_clzll(low)));
            } else if (Wm1) {
                d = min(d, pos + 1 + __builtin_clzll(Wm1));
            }
            const unsigned long long high = (W0 >> pos) >> 1;
            if (high) {
                d = min(d, __builtin_ctzll(high) + 1);
            } else if (Wp1) {
                d = min(d, 64 - pos + __builtin_ctzll(Wp1));
            }
            gt[i] = (float)min(d, RADIUS_I);
        }
    }

    // ---- row max of gt; num/den partials ----
    float dmax = gt[0];
#pragma unroll
    for (int i = 1; i < EPT; ++i) dmax = fmaxf(dmax, gt[i]);

    float num = 0.0f, den = 0.0f;
#pragma unroll
    for (int i = 0; i < EPT; ++i) {
        num += fabsf(pred[i] - gt[i]) * mf[i];
        den += mf[i];
    }
#pragma unroll
    for (int off = 32; off > 0; off >>= 1) {
        num += __shfl_xor(num, off, 64);
        den += __shfl_xor(den, off, 64);
        dmax = fmaxf(dmax, __shfl_xor(dmax, off, 64));
    }
    if (lane == 0) { sredN[wave] = num; sredD[wave] = den; swsum[wave] = dmax; }
    __syncthreads();

    // ---- epilogue: wave 0 only, lane-parallel ----
    if (wave == 0) {
        float ns = (lane < NWAVES) ? sredN[lane] : 0.0f;
        float ds = (lane < NWAVES) ? sredD[lane] : 0.0f;
        float mx = (lane < NWAVES) ? swsum[lane] : 0.0f;
#pragma unroll
        for (int off = 8; off > 0; off >>= 1) {
            ns += __shfl_xor(ns, off, 64);
            ds += __shfl_xor(ds, off, 64);
            mx = fmaxf(mx, __shfl_xor(mx, off, 64));
        }
        // lanes 0..15 all hold block totals now
        const float scale = mx + 1e-6f;

        unsigned int old = 0;
        if (lane == 0) {
            __hip_atomic_store(&partials[row], ns / scale,
                               __ATOMIC_RELAXED, __HIP_MEMORY_SCOPE_AGENT);
            __hip_atomic_store(&partials[NROWS + row], ds,
                               __ATOMIC_RELAXED, __HIP_MEMORY_SCOPE_AGENT);
            old = __hip_atomic_fetch_add(counter, 1u,
                               __ATOMIC_ACQ_REL, __HIP_MEMORY_SCOPE_AGENT);
        }
        old = __shfl(old, 0, 64);
        if ((old % NROWS) == NROWS - 1) {
            // last block: 16 lanes load 16 partials in parallel (relaxed;
            // ordered by the ACQ_REL fetch_add above)
            float v = (lane < 2 * NROWS)
                    ? __hip_atomic_load(&partials[lane],
                          __ATOMIC_RELAXED, __HIP_MEMORY_SCOPE_AGENT)
                    : 0.0f;
            float num_all = (lane < NROWS) ? v : 0.0f;
            float den_all = (lane >= NROWS && lane < 2 * NROWS) ? v : 0.0f;
#pragma unroll
            for (int off = 8; off > 0; off >>= 1) {
                num_all += __shfl_xor(num_all, off, 64);
                den_all += __shfl_xor(den_all, off, 64);
            }
            if (lane == 0) out[0] = num_all / (den_all + 1e-6f);
        }
    }
}

extern "C" void kernel_launch(void* const* d_in, const int* in_sizes, int n_in,
                              void* d_out, int out_size, void* d_ws, size_t ws_size,
                              hipStream_t stream) {
    const float* vel = (const float*)d_in[0];
    const int*   bnd = (const int*)d_in[1];
    const int*   msk = (const int*)d_in[2];
    (void)in_sizes; (void)n_in; (void)ws_size; (void)out_size;

    float* partials = (float*)d_ws;                       // 16 floats
    unsigned int* counter = (unsigned int*)((char*)d_ws + 64);

    aml_row_kernel<<<NROWS, BLOCK, 0, stream>>>(vel, bnd, msk, partials,
                                                counter, (float*)d_out);
}